// Round 5
// baseline (750.304 us; speedup 1.0000x reference)
//
#include <hip/hip_runtime.h>
#include <cstdint>
#include <cstddef>

// ---------- types / helpers ----------
typedef __bf16 bf16x8 __attribute__((ext_vector_type(8)));
typedef float  f32x4  __attribute__((ext_vector_type(4)));

__device__ __forceinline__ unsigned short f2bf(float f) {
  unsigned int u = __float_as_uint(f);
  u += 0x7FFFu + ((u >> 16) & 1u);            // RNE
  return (unsigned short)(u >> 16);
}
__device__ __forceinline__ float bf2f(unsigned short s) {
  return __uint_as_float(((unsigned int)s) << 16);
}
__device__ __forceinline__ unsigned int pk2bf(float a, float b) {
  return (unsigned int)f2bf(a) | ((unsigned int)f2bf(b) << 16);
}

__device__ __forceinline__ void gload_lds16(const void* g, void* l) {
  __builtin_amdgcn_global_load_lds(
      (const __attribute__((address_space(1))) unsigned int*)g,
      (__attribute__((address_space(3))) unsigned int*)l, 16, 0, 0);
}

// XCD slab swizzle (all GEMM grids are (nb, 64), nb % 8 == 0).
// id%8 = XCD (round-robin dispatch heuristic); each XCD owns an N-slab of
// nb/8 x-blocks (W slab stays L2-resident); y runs lock-step across XCDs so
// all 8 XCDs touch the same A row-tile concurrently (one HBM fetch, L3 serves).
__device__ __forceinline__ void swizzle_xy(int& bx, int& by) {
  const int id  = blockIdx.y * gridDim.x + blockIdx.x;
  const int xcd = id & 7;
  const int s   = id >> 3;
  const int slabW = gridDim.x >> 3;
  bx = xcd * slabW + (s >> 6);   // gridDim.y == 64
  by = s & 63;
}

// ---------- generic NT bf16 GEMM: C[M,N] = A[M,K] @ W[N,K]^T ----------
// EPI 0: store bf16. EPI 1: store f32 (acc + aux_f32).
template<int EPI>
__global__ __launch_bounds__(256)
void gemm_nt(const unsigned short* __restrict__ A,
             const unsigned short* __restrict__ W,
             void* __restrict__ Cout, const void* __restrict__ aux,
             int M, int N, int K)
{
  __shared__ unsigned short As[128 * 64];
  __shared__ unsigned short Ws[128 * 64];
  const int tid  = threadIdx.x;
  const int wave = tid >> 6;
  const int lane = tid & 63;
  int bx, by; swizzle_xy(bx, by);
  const int m0 = by << 7;
  const int n0 = bx << 7;
  const int wm = (wave >> 1) << 6;
  const int wn = (wave & 1) << 6;

  f32x4 acc[4][4];
#pragma unroll
  for (int i = 0; i < 4; i++)
#pragma unroll
    for (int j = 0; j < 4; j++) acc[i][j] = (f32x4){0.f, 0.f, 0.f, 0.f};

  const int srow = lane >> 3;
  const int kc   = lane & 7;
  const int sc   = kc ^ srow;          // XOR chunk swizzle
  const unsigned short* pA = A + (size_t)(m0 + wave * 32 + srow) * K + sc * 8;
  const unsigned short* pW = W + (size_t)(n0 + wave * 32 + srow) * K + sc * 8;
  const size_t rstep = (size_t)8 * K;

  const int lhi = lane >> 4;
  const int l15 = lane & 15;
  const int x7  = lane & 7;
  int aoff[4], woff[4];
#pragma unroll
  for (int t = 0; t < 4; t++) {
    aoff[t] = (wm + t * 16 + l15) * 64;
    woff[t] = (wn + t * 16 + l15) * 64;
  }
  const int pos0 = (lhi ^ x7) * 8;

  for (int k0 = 0; k0 < K; k0 += 64) {
    __syncthreads();
#pragma unroll
    for (int c = 0; c < 4; c++) {
      gload_lds16(pA + (size_t)c * rstep, &As[(wave * 32 + c * 8) * 64]);
      gload_lds16(pW + (size_t)c * rstep, &Ws[(wave * 32 + c * 8) * 64]);
    }
    pA += 64; pW += 64;
    __syncthreads();
#pragma unroll
    for (int ks = 0; ks < 2; ks++) {
      const int p = pos0 ^ (ks * 32);
      bf16x8 af[4], wf[4];
#pragma unroll
      for (int t = 0; t < 4; t++) af[t] = *(const bf16x8*)&As[aoff[t] + p];
#pragma unroll
      for (int t = 0; t < 4; t++) wf[t] = *(const bf16x8*)&Ws[woff[t] + p];
#pragma unroll
      for (int i = 0; i < 4; i++)
#pragma unroll
        for (int j = 0; j < 4; j++)
          acc[i][j] = __builtin_amdgcn_mfma_f32_16x16x32_bf16(af[i], wf[j], acc[i][j], 0, 0, 0);
    }
  }

  const int erow = lhi * 4;
#pragma unroll
  for (int i = 0; i < 4; i++) {
    const int rb = m0 + wm + i * 16 + erow;
#pragma unroll
    for (int j = 0; j < 4; j++) {
      const int col = n0 + wn + j * 16 + l15;
#pragma unroll
      for (int r = 0; r < 4; r++) {
        const size_t idx = (size_t)(rb + r) * N + col;
        const float v = acc[i][j][r];
        if (EPI == 0) {
          ((unsigned short*)Cout)[idx] = f2bf(v);
        } else {
          ((float*)Cout)[idx] = v + ((const float*)aux)[idx];
        }
      }
    }
  }
}

// ---------- fused SwiGLU dual GEMM: out = silu(A Wg^T) * (A Wh^T), bf16 ----------
// Shares the A-tile across both accumulators: 576 LDS-bytes/MFMA vs 768 in the
// single GEMM, and removes the 64MB gate round-trip entirely.
__global__ __launch_bounds__(256)
void gemm_swiglu(const unsigned short* __restrict__ A,
                 const unsigned short* __restrict__ Wg,
                 const unsigned short* __restrict__ Wh,
                 unsigned short* __restrict__ Cout,
                 int M, int N, int K)
{
  __shared__ unsigned short As[128 * 64];
  __shared__ unsigned short Gs[128 * 64];
  __shared__ unsigned short Hs[128 * 64];
  const int tid  = threadIdx.x;
  const int wave = tid >> 6;
  const int lane = tid & 63;
  int bx, by; swizzle_xy(bx, by);
  const int m0 = by << 7;
  const int n0 = bx << 7;
  const int wm = (wave >> 1) << 6;
  const int wn = (wave & 1) << 6;

  f32x4 accg[4][4], acch[4][4];
#pragma unroll
  for (int i = 0; i < 4; i++)
#pragma unroll
    for (int j = 0; j < 4; j++) {
      accg[i][j] = (f32x4){0.f, 0.f, 0.f, 0.f};
      acch[i][j] = (f32x4){0.f, 0.f, 0.f, 0.f};
    }

  const int srow = lane >> 3;
  const int kc   = lane & 7;
  const int sc   = kc ^ srow;
  const unsigned short* pA = A  + (size_t)(m0 + wave * 32 + srow) * K + sc * 8;
  const unsigned short* pG = Wg + (size_t)(n0 + wave * 32 + srow) * K + sc * 8;
  const unsigned short* pH = Wh + (size_t)(n0 + wave * 32 + srow) * K + sc * 8;
  const size_t rstep = (size_t)8 * K;

  const int lhi = lane >> 4;
  const int l15 = lane & 15;
  const int x7  = lane & 7;
  int aoff[4], woff[4];
#pragma unroll
  for (int t = 0; t < 4; t++) {
    aoff[t] = (wm + t * 16 + l15) * 64;
    woff[t] = (wn + t * 16 + l15) * 64;
  }
  const int pos0 = (lhi ^ x7) * 8;

  for (int k0 = 0; k0 < K; k0 += 64) {
    __syncthreads();
#pragma unroll
    for (int c = 0; c < 4; c++) {
      gload_lds16(pA + (size_t)c * rstep, &As[(wave * 32 + c * 8) * 64]);
      gload_lds16(pG + (size_t)c * rstep, &Gs[(wave * 32 + c * 8) * 64]);
      gload_lds16(pH + (size_t)c * rstep, &Hs[(wave * 32 + c * 8) * 64]);
    }
    pA += 64; pG += 64; pH += 64;
    __syncthreads();
#pragma unroll
    for (int ks = 0; ks < 2; ks++) {
      const int p = pos0 ^ (ks * 32);
      bf16x8 af[4], gf[4], hf[4];
#pragma unroll
      for (int t = 0; t < 4; t++) af[t] = *(const bf16x8*)&As[aoff[t] + p];
#pragma unroll
      for (int t = 0; t < 4; t++) gf[t] = *(const bf16x8*)&Gs[woff[t] + p];
#pragma unroll
      for (int t = 0; t < 4; t++) hf[t] = *(const bf16x8*)&Hs[woff[t] + p];
#pragma unroll
      for (int i = 0; i < 4; i++)
#pragma unroll
        for (int j = 0; j < 4; j++) {
          accg[i][j] = __builtin_amdgcn_mfma_f32_16x16x32_bf16(af[i], gf[j], accg[i][j], 0, 0, 0);
          acch[i][j] = __builtin_amdgcn_mfma_f32_16x16x32_bf16(af[i], hf[j], acch[i][j], 0, 0, 0);
        }
    }
  }

  const int erow = lhi * 4;
#pragma unroll
  for (int i = 0; i < 4; i++) {
    const int rb = m0 + wm + i * 16 + erow;
#pragma unroll
    for (int j = 0; j < 4; j++) {
      const int col = n0 + wn + j * 16 + l15;
#pragma unroll
      for (int r = 0; r < 4; r++) {
        const size_t idx = (size_t)(rb + r) * N + col;
        const float g  = accg[i][j][r];
        const float hv = acch[i][j][r];
        Cout[idx] = f2bf(hv * g / (1.0f + __expf(-g)));
      }
    }
  }
}

// ---------- flash attention (S^T formulation, no running max, swizzled LDS) ----------
#define CEXP 0.1803368801111137f   // log2(e)/8

__global__ __launch_bounds__(256, 2)
void flash_attn(const unsigned short* __restrict__ qkv,
                unsigned short* __restrict__ out)
{
  __shared__ unsigned short QP[128 * 64];  // Q tile, reused as P
  __shared__ unsigned short Ks[64 * 64];
  __shared__ unsigned short Vt[64 * 64];   // V^T: [d][kv]
  const int tid  = threadIdx.x;
  const int wave = tid >> 6;
  const int lane = tid & 63;
  const int b  = blockIdx.x >> 4;
  const int h  = blockIdx.x & 15;
  const int qb = blockIdx.y;
  const size_t rowbase = (size_t)b * 1024 * 3072;
  const int l15 = lane & 15, lhi = lane >> 4;
  const int l7  = l15 & 7;
  const int srcb = (lane & 48) + lhi * 4;

#pragma unroll
  for (int i = 0; i < 4; i++) {
    const int ci = tid + 256 * i;
    const int r = ci >> 3, c = ci & 7;
    *(uint4*)&QP[r * 64 + c * 8] =
        *(const uint4*)&qkv[rowbase + (size_t)(qb * 128 + r) * 3072 + h * 64 + (c ^ (r & 7)) * 8];
  }
  __syncthreads();
  bf16x8 qf[2][2];
#pragma unroll
  for (int mt = 0; mt < 2; mt++)
#pragma unroll
    for (int ks = 0; ks < 2; ks++)
      qf[mt][ks] = *(const bf16x8*)&QP[(wave * 32 + mt * 16 + l15) * 64 + (((ks * 4 + lhi) ^ l7)) * 8];

  float lst[2] = {0.0f, 0.0f};
  f32x4 o[2][4];
#pragma unroll
  for (int mt = 0; mt < 2; mt++)
#pragma unroll
    for (int ct = 0; ct < 4; ct++) o[mt][ct] = (f32x4){0.f, 0.f, 0.f, 0.f};

  const int sr0 = tid >> 3;
  const int sc8 = tid & 7;
  uint4 kr[2], vr[2];
#pragma unroll
  for (int i = 0; i < 2; i++) {
    kr[i] = *(const uint4*)&qkv[rowbase + (size_t)(sr0 + 32 * i) * 3072 + 1024 + h * 64 + sc8 * 8];
    vr[i] = *(const uint4*)&qkv[rowbase + (size_t)(2 * sr0 + i) * 3072 + 2048 + h * 64 + sc8 * 8];
  }

  for (int j = 0; j < 16; j++) {
    __syncthreads();
#pragma unroll
    for (int i = 0; i < 2; i++) {
      const int r = sr0 + 32 * i;
      *(uint4*)&Ks[r * 64 + (sc8 ^ (r & 7)) * 8] = kr[i];
    }
    {
      const unsigned short* e0 = (const unsigned short*)&vr[0];
      const unsigned short* e1 = (const unsigned short*)&vr[1];
      unsigned int* VtD = (unsigned int*)Vt;
#pragma unroll
      for (int t2 = 0; t2 < 8; t2++) {
        const int d  = sc8 * 8 + t2;
        const int cs = ((sr0 >> 2) ^ t2 ^ sc8) & 7;
        VtD[d * 32 + cs * 4 + (sr0 & 3)] =
            (unsigned int)e0[t2] | ((unsigned int)e1[t2] << 16);
      }
    }
    __syncthreads();

    f32x4 s[4][2];
#pragma unroll
    for (int nt = 0; nt < 4; nt++)
#pragma unroll
      for (int mt = 0; mt < 2; mt++) s[nt][mt] = (f32x4){0.f, 0.f, 0.f, 0.f};
#pragma unroll
    for (int ks = 0; ks < 2; ks++) {
      bf16x8 kf[4];
#pragma unroll
      for (int nt = 0; nt < 4; nt++)
        kf[nt] = *(const bf16x8*)&Ks[(nt * 16 + l15) * 64 + (((ks * 4 + lhi) ^ l7)) * 8];
#pragma unroll
      for (int nt = 0; nt < 4; nt++)
#pragma unroll
        for (int mt = 0; mt < 2; mt++)
          s[nt][mt] = __builtin_amdgcn_mfma_f32_16x16x32_bf16(kf[nt], qf[mt][ks], s[nt][mt], 0, 0, 0);
    }

    {
      const int jn = ((j + 1) & 15) * 64;
#pragma unroll
      for (int i = 0; i < 2; i++) {
        kr[i] = *(const uint4*)&qkv[rowbase + (size_t)(jn + sr0 + 32 * i) * 3072 + 1024 + h * 64 + sc8 * 8];
        vr[i] = *(const uint4*)&qkv[rowbase + (size_t)(jn + 2 * sr0 + i) * 3072 + 2048 + h * 64 + sc8 * 8];
      }
    }

#pragma unroll
    for (int mt = 0; mt < 2; mt++) {
      float ls = 0.0f;
      const int prow = (wave * 32 + mt * 16 + l15) * 64;
#pragma unroll
      for (int nt = 0; nt < 4; nt++) {
        const float p0 = exp2f(s[nt][mt][0] * CEXP);
        const float p1 = exp2f(s[nt][mt][1] * CEXP);
        const float p2 = exp2f(s[nt][mt][2] * CEXP);
        const float p3 = exp2f(s[nt][mt][3] * CEXP);
        ls += (p0 + p1) + (p2 + p3);
        const int pos = ((nt * 2 + (lhi >> 1)) ^ l7);
        uint2 pk; pk.x = pk2bf(p0, p1); pk.y = pk2bf(p2, p3);
        *(uint2*)&QP[prow + pos * 8 + (lhi & 1) * 4] = pk;
      }
      lst[mt] += ls;
    }

#pragma unroll
    for (int ks = 0; ks < 2; ks++) {
      bf16x8 pf[2], vf[4];
#pragma unroll
      for (int mt = 0; mt < 2; mt++)
        pf[mt] = *(const bf16x8*)&QP[(wave * 32 + mt * 16 + l15) * 64 + (((ks * 4 + lhi) ^ l7)) * 8];
#pragma unroll
      for (int ct = 0; ct < 4; ct++) {
        const int d  = ct * 16 + l15;
        const int cs = ((ks * 4 + lhi) ^ l7 ^ (ct * 2 + (l15 >> 3))) & 7;
        vf[ct] = *(const bf16x8*)&Vt[d * 64 + cs * 8];
      }
#pragma unroll
      for (int mt = 0; mt < 2; mt++)
#pragma unroll
        for (int ct = 0; ct < 4; ct++)
          o[mt][ct] = __builtin_amdgcn_mfma_f32_16x16x32_bf16(pf[mt], vf[ct], o[mt][ct], 0, 0, 0);
    }
  }

#pragma unroll
  for (int mt = 0; mt < 2; mt++) {
    float l = lst[mt];
    l += __shfl_xor(l, 16, 64);
    l += __shfl_xor(l, 32, 64);
#pragma unroll
    for (int r = 0; r < 4; r++) {
      const float rl = 1.0f / __shfl(l, srcb + r, 64);
      const size_t row = (size_t)b * 1024 + qb * 128 + wave * 32 + mt * 16 + lhi * 4 + r;
#pragma unroll
      for (int ct = 0; ct < 4; ct++)
        out[row * 1024 + h * 64 + ct * 16 + l15] = f2bf(o[mt][ct][r] * rl);
    }
  }
}

// ---------- tc-RMSNorm ----------
__global__ __launch_bounds__(256)
void tc_rmsnorm_k(const float* __restrict__ x, const float* __restrict__ gamma,
                  const float* __restrict__ beta, unsigned short* __restrict__ outp)
{
  const int row = blockIdx.x;
  const int b = row >> 10;
  const int tid = threadIdx.x;
  const float4 v = *(const float4*)(x + (size_t)row * 1024 + tid * 4);
  float ss = v.x * v.x + v.y * v.y + v.z * v.z + v.w * v.w;
#pragma unroll
  for (int m = 1; m < 64; m <<= 1) ss += __shfl_xor(ss, m, 64);
  __shared__ float ws4[4];
  if ((tid & 63) == 0) ws4[tid >> 6] = ss;
  __syncthreads();
  const float inv = rsqrtf((ws4[0] + ws4[1] + ws4[2] + ws4[3]) * (1.0f / 1024.0f) + 1e-6f);
  const float4 g  = *(const float4*)(gamma + b * 1024 + tid * 4);
  const float4 be = *(const float4*)(beta  + b * 1024 + tid * 4);
  ushort4 ov;
  ov.x = f2bf(g.x * v.x * inv + be.x);
  ov.y = f2bf(g.y * v.y * inv + be.y);
  ov.z = f2bf(g.z * v.z * inv + be.z);
  ov.w = f2bf(g.w * v.w * inv + be.w);
  *(ushort4*)(outp + (size_t)row * 1024 + tid * 4) = ov;
}

// ---------- small helpers ----------
__global__ __launch_bounds__(256)
void convert_bf16(const float* __restrict__ in, unsigned short* __restrict__ outp, int n)
{
  const int i = (blockIdx.x * 256 + threadIdx.x) * 4;
  if (i >= n) return;
  const float4 v = *(const float4*)(in + i);
  ushort4 ov;
  ov.x = f2bf(v.x); ov.y = f2bf(v.y); ov.z = f2bf(v.z); ov.w = f2bf(v.w);
  *(ushort4*)(outp + i) = ov;
}

__global__ __launch_bounds__(256)
void tc_linear(const float* __restrict__ t, const float* __restrict__ w,
               const float* __restrict__ bias, float* __restrict__ outp)
{
  const int idx = blockIdx.x * 256 + threadIdx.x;
  const int b = idx & 7;
  const int d = idx >> 3;
  const float* tr = t + b * 256;
  const float* wr = w + (size_t)d * 256;
  float s = bias[d];
#pragma unroll 4
  for (int k = 0; k < 256; k += 4) {
    const float4 a  = *(const float4*)(tr + k);
    const float4 ww = *(const float4*)(wr + k);
    s += a.x * ww.x + a.y * ww.y + a.z * ww.z + a.w * ww.w;
  }
  outp[b * 1024 + d] = s;
}

// ---------- orchestration ----------
extern "C" void kernel_launch(void* const* d_in, const int* in_sizes, int n_in,
                              void* d_out, int out_size, void* d_ws, size_t ws_size,
                              hipStream_t stream)
{
  (void)in_sizes; (void)n_in; (void)out_size; (void)ws_size;
  const float* x     = (const float*)d_in[0];
  const float* t     = (const float*)d_in[1];
  const float* Wq    = (const float*)d_in[2];
  const float* Wk    = (const float*)d_in[3];
  const float* Wv    = (const float*)d_in[4];
  const float* Wo    = (const float*)d_in[5];
  const float* g1w   = (const float*)d_in[6];
  const float* g1b   = (const float*)d_in[7];
  const float* b1w   = (const float*)d_in[8];
  const float* b1b   = (const float*)d_in[9];
  const float* g2w   = (const float*)d_in[10];
  const float* g2b   = (const float*)d_in[11];
  const float* b2w   = (const float*)d_in[12];
  const float* b2b   = (const float*)d_in[13];
  const float* gatew = (const float*)d_in[14];
  const float* hidw  = (const float*)d_in[15];
  const float* outw  = (const float*)d_in[16];
  float* out = (float*)d_out;

  char* ws = (char*)d_ws;
  unsigned short* Wqkv_bf = (unsigned short*)(ws);              // [3072,1024]
  unsigned short* Wo_bf   = (unsigned short*)(ws + 6291456);    // [1024,1024]
  unsigned short* gate_bf = (unsigned short*)(ws + 8388608);    // [4096,1024]
  unsigned short* hid_bf  = (unsigned short*)(ws + 16777216);   // [4096,1024]
  unsigned short* outw_bf = (unsigned short*)(ws + 25165824);   // [1024,4096]
  float*          gb      = (float*)(ws + 33554432);            // 4 x [8,1024]
  unsigned short* h_bf    = (unsigned short*)(ws + 33685504);   // [8192,1024]
  float*          x1      = (float*)(ws + 50462720);            // [8192,1024] f32
  unsigned short* big     = (unsigned short*)(ws + 84017152);   // [8192,4096]

  convert_bf16<<<1024, 256, 0, stream>>>(Wq, Wqkv_bf,           1048576);
  convert_bf16<<<1024, 256, 0, stream>>>(Wk, Wqkv_bf + 1048576, 1048576);
  convert_bf16<<<1024, 256, 0, stream>>>(Wv, Wqkv_bf + 2097152, 1048576);
  convert_bf16<<<1024, 256, 0, stream>>>(Wo, Wo_bf,             1048576);
  convert_bf16<<<4096, 256, 0, stream>>>(gatew, gate_bf, 4194304);
  convert_bf16<<<4096, 256, 0, stream>>>(hidw,  hid_bf,  4194304);
  convert_bf16<<<4096, 256, 0, stream>>>(outw,  outw_bf, 4194304);
  tc_linear<<<32, 256, 0, stream>>>(t, g1w, g1b, gb);
  tc_linear<<<32, 256, 0, stream>>>(t, b1w, b1b, gb + 8192);
  tc_linear<<<32, 256, 0, stream>>>(t, g2w, g2b, gb + 16384);
  tc_linear<<<32, 256, 0, stream>>>(t, b2w, b2b, gb + 24576);

  tc_rmsnorm_k<<<8192, 256, 0, stream>>>(x, gb, gb + 8192, h_bf);
  gemm_nt<0><<<dim3(24, 64), 256, 0, stream>>>(h_bf, Wqkv_bf, big, nullptr, 8192, 3072, 1024);
  flash_attn<<<dim3(128, 8), 256, 0, stream>>>(big, h_bf);
  gemm_nt<1><<<dim3(8, 64), 256, 0, stream>>>(h_bf, Wo_bf, x1, x, 8192, 1024, 1024);
  tc_rmsnorm_k<<<8192, 256, 0, stream>>>(x1, gb + 16384, gb + 24576, h_bf);
  gemm_swiglu<<<dim3(32, 64), 256, 0, stream>>>(h_bf, gate_bf, hid_bf, big, 8192, 4096, 1024);
  gemm_nt<1><<<dim3(8, 64), 256, 0, stream>>>(big, outw_bf, out, x1, 8192, 1024, 4096);
}

// Round 6
// 615.541 us; speedup vs baseline: 1.2189x; 1.2189x over previous
//
#include <hip/hip_runtime.h>
#include <cstdint>
#include <cstddef>

// ---------- types / helpers ----------
typedef __bf16 bf16x8 __attribute__((ext_vector_type(8)));
typedef float  f32x4  __attribute__((ext_vector_type(4)));

__device__ __forceinline__ unsigned short f2bf(float f) {
  unsigned int u = __float_as_uint(f);
  u += 0x7FFFu + ((u >> 16) & 1u);            // RNE
  return (unsigned short)(u >> 16);
}
__device__ __forceinline__ float bf2f(unsigned short s) {
  return __uint_as_float(((unsigned int)s) << 16);
}
__device__ __forceinline__ unsigned int pk2bf(float a, float b) {
  return (unsigned int)f2bf(a) | ((unsigned int)f2bf(b) << 16);
}

__device__ __forceinline__ void gload_lds16(const void* g, void* l) {
  __builtin_amdgcn_global_load_lds(
      (const __attribute__((address_space(1))) unsigned int*)g,
      (__attribute__((address_space(3))) unsigned int*)l, 16, 0, 0);
}

// ---------- 128x256-tile NT bf16 GEMM (for K=1024 wide-N GEMMs) ----------
// C[M,N] = A[M,K] @ W[N,K]^T. 4 waves, each 64x128: acc 4x8 (128 AGPR).
// Intensity: 256 MFMA per (48KB staged + 96KB read) = 576 B/MFMA vs 768 at 128^2.
// __launch_bounds__(256,2): cap 256 regs/wave -> guaranteed 2 blocks/CU.
// EPI 0: store bf16. EPI 2: store bf16 silu(aux_bf16)*acc (in-place safe).
template<int EPI>
__global__ __launch_bounds__(256, 2)
void gemm_big(const unsigned short* __restrict__ A,
              const unsigned short* __restrict__ W,
              unsigned short* __restrict__ Cout, const unsigned short* __restrict__ aux,
              int M, int N, int K)
{
  __shared__ unsigned short As[128 * 64];   // 16 KB
  __shared__ unsigned short Ws[256 * 64];   // 32 KB
  const int tid  = threadIdx.x;
  const int wave = tid >> 6;
  const int lane = tid & 63;
  const int m0 = blockIdx.y << 7;
  const int n0 = blockIdx.x << 8;
  const int wm = (wave >> 1) << 6;
  const int wn = (wave & 1) << 7;

  f32x4 acc[4][8];
#pragma unroll
  for (int i = 0; i < 4; i++)
#pragma unroll
    for (int j = 0; j < 8; j++) acc[i][j] = (f32x4){0.f, 0.f, 0.f, 0.f};

  const int srow = lane >> 3;
  const int kc   = lane & 7;
  const int sc   = kc ^ srow;          // XOR chunk swizzle
  const unsigned short* pA = A + (size_t)(m0 + wave * 32 + srow) * K + sc * 8;
  const unsigned short* pW = W + (size_t)(n0 + wave * 64 + srow) * K + sc * 8;
  const size_t rstep = (size_t)8 * K;

  const int lhi = lane >> 4;
  const int l15 = lane & 15;
  const int x7  = lane & 7;
  const int pos0 = (lhi ^ x7) * 8;

  for (int k0 = 0; k0 < K; k0 += 64) {
    __syncthreads();
#pragma unroll
    for (int c = 0; c < 4; c++)
      gload_lds16(pA + (size_t)c * rstep, &As[(wave * 32 + c * 8) * 64]);
#pragma unroll
    for (int c = 0; c < 8; c++)
      gload_lds16(pW + (size_t)c * rstep, &Ws[(wave * 64 + c * 8) * 64]);
    pA += 64; pW += 64;
    __syncthreads();
#pragma unroll
    for (int ks = 0; ks < 2; ks++) {
      const int p = pos0 ^ (ks * 32);
      bf16x8 af[4];
#pragma unroll
      for (int t = 0; t < 4; t++) af[t] = *(const bf16x8*)&As[(wm + t * 16 + l15) * 64 + p];
#pragma unroll
      for (int j = 0; j < 8; j++) {
        const bf16x8 wf = *(const bf16x8*)&Ws[(wn + j * 16 + l15) * 64 + p];
#pragma unroll
        for (int i = 0; i < 4; i++)
          acc[i][j] = __builtin_amdgcn_mfma_f32_16x16x32_bf16(af[i], wf, acc[i][j], 0, 0, 0);
      }
    }
  }

  const int erow = lhi * 4;
#pragma unroll
  for (int i = 0; i < 4; i++) {
    const int rb = m0 + wm + i * 16 + erow;
#pragma unroll
    for (int j = 0; j < 8; j++) {
      const int col = n0 + wn + j * 16 + l15;
#pragma unroll
      for (int r = 0; r < 4; r++) {
        const size_t idx = (size_t)(rb + r) * N + col;
        const float v = acc[i][j][r];
        if (EPI == 0) {
          Cout[idx] = f2bf(v);
        } else {
          const float g = bf2f(aux[idx]);
          Cout[idx] = f2bf(v * g / (1.0f + __expf(-g)));
        }
      }
    }
  }
}

// ---------- 128x128-tile NT bf16 GEMM (N=1024 GEMMs), EPI 1: f32 acc+aux ----------
template<int EPI>
__global__ __launch_bounds__(256)
void gemm_nt(const unsigned short* __restrict__ A,
             const unsigned short* __restrict__ W,
             void* __restrict__ Cout, const void* __restrict__ aux,
             int M, int N, int K)
{
  __shared__ unsigned short As[128 * 64];
  __shared__ unsigned short Ws[128 * 64];
  const int tid  = threadIdx.x;
  const int wave = tid >> 6;
  const int lane = tid & 63;
  const int m0 = blockIdx.y << 7;
  const int n0 = blockIdx.x << 7;
  const int wm = (wave >> 1) << 6;
  const int wn = (wave & 1) << 6;

  f32x4 acc[4][4];
#pragma unroll
  for (int i = 0; i < 4; i++)
#pragma unroll
    for (int j = 0; j < 4; j++) acc[i][j] = (f32x4){0.f, 0.f, 0.f, 0.f};

  const int srow = lane >> 3;
  const int kc   = lane & 7;
  const int sc   = kc ^ srow;
  const unsigned short* pA = A + (size_t)(m0 + wave * 32 + srow) * K + sc * 8;
  const unsigned short* pW = W + (size_t)(n0 + wave * 32 + srow) * K + sc * 8;
  const size_t rstep = (size_t)8 * K;

  const int lhi = lane >> 4;
  const int l15 = lane & 15;
  const int x7  = lane & 7;
  int aoff[4], woff[4];
#pragma unroll
  for (int t = 0; t < 4; t++) {
    aoff[t] = (wm + t * 16 + l15) * 64;
    woff[t] = (wn + t * 16 + l15) * 64;
  }
  const int pos0 = (lhi ^ x7) * 8;

  for (int k0 = 0; k0 < K; k0 += 64) {
    __syncthreads();
#pragma unroll
    for (int c = 0; c < 4; c++) {
      gload_lds16(pA + (size_t)c * rstep, &As[(wave * 32 + c * 8) * 64]);
      gload_lds16(pW + (size_t)c * rstep, &Ws[(wave * 32 + c * 8) * 64]);
    }
    pA += 64; pW += 64;
    __syncthreads();
#pragma unroll
    for (int ks = 0; ks < 2; ks++) {
      const int p = pos0 ^ (ks * 32);
      bf16x8 af[4], wf[4];
#pragma unroll
      for (int t = 0; t < 4; t++) af[t] = *(const bf16x8*)&As[aoff[t] + p];
#pragma unroll
      for (int t = 0; t < 4; t++) wf[t] = *(const bf16x8*)&Ws[woff[t] + p];
#pragma unroll
      for (int i = 0; i < 4; i++)
#pragma unroll
        for (int j = 0; j < 4; j++)
          acc[i][j] = __builtin_amdgcn_mfma_f32_16x16x32_bf16(af[i], wf[j], acc[i][j], 0, 0, 0);
    }
  }

  const int erow = lhi * 4;
#pragma unroll
  for (int i = 0; i < 4; i++) {
    const int rb = m0 + wm + i * 16 + erow;
#pragma unroll
    for (int j = 0; j < 4; j++) {
      const int col = n0 + wn + j * 16 + l15;
#pragma unroll
      for (int r = 0; r < 4; r++) {
        const size_t idx = (size_t)(rb + r) * N + col;
        const float v = acc[i][j][r];
        if (EPI == 0) {
          ((unsigned short*)Cout)[idx] = f2bf(v);
        } else {
          ((float*)Cout)[idx] = v + ((const float*)aux)[idx];
        }
      }
    }
  }
}

// ---------- flash attention (S^T formulation, no running max, swizzled LDS) ----------
#define CEXP 0.1803368801111137f   // log2(e)/8

__global__ __launch_bounds__(256, 2)
void flash_attn(const unsigned short* __restrict__ qkv,
                unsigned short* __restrict__ out)
{
  __shared__ unsigned short QP[128 * 64];  // Q tile, reused as P
  __shared__ unsigned short Ks[64 * 64];
  __shared__ unsigned short Vt[64 * 64];   // V^T: [d][kv]
  const int tid  = threadIdx.x;
  const int wave = tid >> 6;
  const int lane = tid & 63;
  const int b  = blockIdx.x >> 4;
  const int h  = blockIdx.x & 15;
  const int qb = blockIdx.y;
  const size_t rowbase = (size_t)b * 1024 * 3072;
  const int l15 = lane & 15, lhi = lane >> 4;
  const int l7  = l15 & 7;
  const int srcb = (lane & 48) + lhi * 4;

#pragma unroll
  for (int i = 0; i < 4; i++) {
    const int ci = tid + 256 * i;
    const int r = ci >> 3, c = ci & 7;
    *(uint4*)&QP[r * 64 + c * 8] =
        *(const uint4*)&qkv[rowbase + (size_t)(qb * 128 + r) * 3072 + h * 64 + (c ^ (r & 7)) * 8];
  }
  __syncthreads();
  bf16x8 qf[2][2];
#pragma unroll
  for (int mt = 0; mt < 2; mt++)
#pragma unroll
    for (int ks = 0; ks < 2; ks++)
      qf[mt][ks] = *(const bf16x8*)&QP[(wave * 32 + mt * 16 + l15) * 64 + (((ks * 4 + lhi) ^ l7)) * 8];

  float lst[2] = {0.0f, 0.0f};
  f32x4 o[2][4];
#pragma unroll
  for (int mt = 0; mt < 2; mt++)
#pragma unroll
    for (int ct = 0; ct < 4; ct++) o[mt][ct] = (f32x4){0.f, 0.f, 0.f, 0.f};

  const int sr0 = tid >> 3;
  const int sc8 = tid & 7;
  uint4 kr[2], vr[2];
#pragma unroll
  for (int i = 0; i < 2; i++) {
    kr[i] = *(const uint4*)&qkv[rowbase + (size_t)(sr0 + 32 * i) * 3072 + 1024 + h * 64 + sc8 * 8];
    vr[i] = *(const uint4*)&qkv[rowbase + (size_t)(2 * sr0 + i) * 3072 + 2048 + h * 64 + sc8 * 8];
  }

  for (int j = 0; j < 16; j++) {
    __syncthreads();
#pragma unroll
    for (int i = 0; i < 2; i++) {
      const int r = sr0 + 32 * i;
      *(uint4*)&Ks[r * 64 + (sc8 ^ (r & 7)) * 8] = kr[i];
    }
    {
      const unsigned short* e0 = (const unsigned short*)&vr[0];
      const unsigned short* e1 = (const unsigned short*)&vr[1];
      unsigned int* VtD = (unsigned int*)Vt;
#pragma unroll
      for (int t2 = 0; t2 < 8; t2++) {
        const int d  = sc8 * 8 + t2;
        const int cs = ((sr0 >> 2) ^ t2 ^ sc8) & 7;
        VtD[d * 32 + cs * 4 + (sr0 & 3)] =
            (unsigned int)e0[t2] | ((unsigned int)e1[t2] << 16);
      }
    }
    __syncthreads();

    f32x4 s[4][2];
#pragma unroll
    for (int nt = 0; nt < 4; nt++)
#pragma unroll
      for (int mt = 0; mt < 2; mt++) s[nt][mt] = (f32x4){0.f, 0.f, 0.f, 0.f};
#pragma unroll
    for (int ks = 0; ks < 2; ks++) {
      bf16x8 kf[4];
#pragma unroll
      for (int nt = 0; nt < 4; nt++)
        kf[nt] = *(const bf16x8*)&Ks[(nt * 16 + l15) * 64 + (((ks * 4 + lhi) ^ l7)) * 8];
#pragma unroll
      for (int nt = 0; nt < 4; nt++)
#pragma unroll
        for (int mt = 0; mt < 2; mt++)
          s[nt][mt] = __builtin_amdgcn_mfma_f32_16x16x32_bf16(kf[nt], qf[mt][ks], s[nt][mt], 0, 0, 0);
    }

    {
      const int jn = ((j + 1) & 15) * 64;
#pragma unroll
      for (int i = 0; i < 2; i++) {
        kr[i] = *(const uint4*)&qkv[rowbase + (size_t)(jn + sr0 + 32 * i) * 3072 + 1024 + h * 64 + sc8 * 8];
        vr[i] = *(const uint4*)&qkv[rowbase + (size_t)(jn + 2 * sr0 + i) * 3072 + 2048 + h * 64 + sc8 * 8];
      }
    }

#pragma unroll
    for (int mt = 0; mt < 2; mt++) {
      float ls = 0.0f;
      const int prow = (wave * 32 + mt * 16 + l15) * 64;
#pragma unroll
      for (int nt = 0; nt < 4; nt++) {
        const float p0 = exp2f(s[nt][mt][0] * CEXP);
        const float p1 = exp2f(s[nt][mt][1] * CEXP);
        const float p2 = exp2f(s[nt][mt][2] * CEXP);
        const float p3 = exp2f(s[nt][mt][3] * CEXP);
        ls += (p0 + p1) + (p2 + p3);
        const int pos = ((nt * 2 + (lhi >> 1)) ^ l7);
        uint2 pk; pk.x = pk2bf(p0, p1); pk.y = pk2bf(p2, p3);
        *(uint2*)&QP[prow + pos * 8 + (lhi & 1) * 4] = pk;
      }
      lst[mt] += ls;
    }

#pragma unroll
    for (int ks = 0; ks < 2; ks++) {
      bf16x8 pf[2], vf[4];
#pragma unroll
      for (int mt = 0; mt < 2; mt++)
        pf[mt] = *(const bf16x8*)&QP[(wave * 32 + mt * 16 + l15) * 64 + (((ks * 4 + lhi) ^ l7)) * 8];
#pragma unroll
      for (int ct = 0; ct < 4; ct++) {
        const int d  = ct * 16 + l15;
        const int cs = ((ks * 4 + lhi) ^ l7 ^ (ct * 2 + (l15 >> 3))) & 7;
        vf[ct] = *(const bf16x8*)&Vt[d * 64 + cs * 8];
      }
#pragma unroll
      for (int mt = 0; mt < 2; mt++)
#pragma unroll
        for (int ct = 0; ct < 4; ct++)
          o[mt][ct] = __builtin_amdgcn_mfma_f32_16x16x32_bf16(pf[mt], vf[ct], o[mt][ct], 0, 0, 0);
    }
  }

#pragma unroll
  for (int mt = 0; mt < 2; mt++) {
    float l = lst[mt];
    l += __shfl_xor(l, 16, 64);
    l += __shfl_xor(l, 32, 64);
#pragma unroll
    for (int r = 0; r < 4; r++) {
      const float rl = 1.0f / __shfl(l, srcb + r, 64);
      const size_t row = (size_t)b * 1024 + qb * 128 + wave * 32 + mt * 16 + lhi * 4 + r;
#pragma unroll
      for (int ct = 0; ct < 4; ct++)
        out[row * 1024 + h * 64 + ct * 16 + l15] = f2bf(o[mt][ct][r] * rl);
    }
  }
}

// ---------- tc-RMSNorm ----------
__global__ __launch_bounds__(256)
void tc_rmsnorm_k(const float* __restrict__ x, const float* __restrict__ gamma,
                  const float* __restrict__ beta, unsigned short* __restrict__ outp)
{
  const int row = blockIdx.x;
  const int b = row >> 10;
  const int tid = threadIdx.x;
  const float4 v = *(const float4*)(x + (size_t)row * 1024 + tid * 4);
  float ss = v.x * v.x + v.y * v.y + v.z * v.z + v.w * v.w;
#pragma unroll
  for (int m = 1; m < 64; m <<= 1) ss += __shfl_xor(ss, m, 64);
  __shared__ float ws4[4];
  if ((tid & 63) == 0) ws4[tid >> 6] = ss;
  __syncthreads();
  const float inv = rsqrtf((ws4[0] + ws4[1] + ws4[2] + ws4[3]) * (1.0f / 1024.0f) + 1e-6f);
  const float4 g  = *(const float4*)(gamma + b * 1024 + tid * 4);
  const float4 be = *(const float4*)(beta  + b * 1024 + tid * 4);
  ushort4 ov;
  ov.x = f2bf(g.x * v.x * inv + be.x);
  ov.y = f2bf(g.y * v.y * inv + be.y);
  ov.z = f2bf(g.z * v.z * inv + be.z);
  ov.w = f2bf(g.w * v.w * inv + be.w);
  *(ushort4*)(outp + (size_t)row * 1024 + tid * 4) = ov;
}

// ---------- fused weight convert: all 7 fp32 weights -> one contiguous bf16 region ----------
// dst elems: [0,1M) Wq | [1M,2M) Wk | [2M,3M) Wv | [3M,4M) Wo | [4M,8M) gate | [8M,12M) hid | [12M,16M) outw
__global__ __launch_bounds__(256)
void convert_all(const float* __restrict__ s0, const float* __restrict__ s1,
                 const float* __restrict__ s2, const float* __restrict__ s3,
                 const float* __restrict__ s4, const float* __restrict__ s5,
                 const float* __restrict__ s6, unsigned short* __restrict__ dst)
{
  const int i = (blockIdx.x * 256 + threadIdx.x) * 4;
  const float* src; int off;
  if (i < 4194304) {
    src = (i < 1048576) ? s0 : (i < 2097152) ? s1 : (i < 3145728) ? s2 : s3;
    off = i & 1048575;
  } else if (i < 8388608)  { src = s4; off = i - 4194304; }
  else if (i < 12582912)   { src = s5; off = i - 8388608; }
  else                     { src = s6; off = i - 12582912; }
  const float4 v = *(const float4*)(src + off);
  ushort4 ov;
  ov.x = f2bf(v.x); ov.y = f2bf(v.y); ov.z = f2bf(v.z); ov.w = f2bf(v.w);
  *(ushort4*)(dst + i) = ov;
}

// ---------- fused tc-linear: all 4 gamma/beta heads in one launch ----------
// outp layout: gamma1|beta1|gamma2|beta2, each [8,1024] f32
__global__ __launch_bounds__(256)
void tc_linear4(const float* __restrict__ t,
                const float* __restrict__ w0, const float* __restrict__ b0,
                const float* __restrict__ w1, const float* __restrict__ b1,
                const float* __restrict__ w2, const float* __restrict__ b2,
                const float* __restrict__ w3, const float* __restrict__ b3,
                float* __restrict__ outp)
{
  const int idx = blockIdx.x * 256 + threadIdx.x;    // 0..32767
  const int which = idx >> 13;
  const int sub = idx & 8191;
  const int b = sub & 7;
  const int d = sub >> 3;
  const float* w  = (which == 0) ? w0 : (which == 1) ? w1 : (which == 2) ? w2 : w3;
  const float* bi = (which == 0) ? b0 : (which == 1) ? b1 : (which == 2) ? b2 : b3;
  const float* tr = t + b * 256;
  const float* wr = w + (size_t)d * 256;
  float s = bi[d];
#pragma unroll 4
  for (int k = 0; k < 256; k += 4) {
    const float4 a  = *(const float4*)(tr + k);
    const float4 ww = *(const float4*)(wr + k);
    s += a.x * ww.x + a.y * ww.y + a.z * ww.z + a.w * ww.w;
  }
  outp[which * 8192 + b * 1024 + d] = s;
}

// ---------- orchestration ----------
extern "C" void kernel_launch(void* const* d_in, const int* in_sizes, int n_in,
                              void* d_out, int out_size, void* d_ws, size_t ws_size,
                              hipStream_t stream)
{
  (void)in_sizes; (void)n_in; (void)out_size; (void)ws_size;
  const float* x     = (const float*)d_in[0];
  const float* t     = (const float*)d_in[1];
  const float* Wq    = (const float*)d_in[2];
  const float* Wk    = (const float*)d_in[3];
  const float* Wv    = (const float*)d_in[4];
  const float* Wo    = (const float*)d_in[5];
  const float* g1w   = (const float*)d_in[6];
  const float* g1b   = (const float*)d_in[7];
  const float* b1w   = (const float*)d_in[8];
  const float* b1b   = (const float*)d_in[9];
  const float* g2w   = (const float*)d_in[10];
  const float* g2b   = (const float*)d_in[11];
  const float* b2w   = (const float*)d_in[12];
  const float* b2b   = (const float*)d_in[13];
  const float* gatew = (const float*)d_in[14];
  const float* hidw  = (const float*)d_in[15];
  const float* outw  = (const float*)d_in[16];
  float* out = (float*)d_out;

  char* ws = (char*)d_ws;
  unsigned short* Wqkv_bf = (unsigned short*)(ws);              // [3072,1024]
  unsigned short* Wo_bf   = (unsigned short*)(ws + 6291456);    // [1024,1024]
  unsigned short* gate_bf = (unsigned short*)(ws + 8388608);    // [4096,1024]
  unsigned short* hid_bf  = (unsigned short*)(ws + 16777216);   // [4096,1024]
  unsigned short* outw_bf = (unsigned short*)(ws + 25165824);   // [1024,4096]
  float*          gb      = (float*)(ws + 33554432);            // 4 x [8,1024]
  unsigned short* h_bf    = (unsigned short*)(ws + 33685504);   // [8192,1024]
  float*          x1      = (float*)(ws + 50462720);            // [8192,1024] f32
  unsigned short* big     = (unsigned short*)(ws + 84017152);   // [8192,4096]

  // all weight converts in one launch (dst regions are contiguous in ws)
  convert_all<<<16384, 256, 0, stream>>>(Wq, Wk, Wv, Wo, gatew, hidw, outw, Wqkv_bf);
  // all 4 gamma/beta linears in one launch
  tc_linear4<<<128, 256, 0, stream>>>(t, g1w, g1b, b1w, b1b, g2w, g2b, b2w, b2b, gb);

  tc_rmsnorm_k<<<8192, 256, 0, stream>>>(x, gb, gb + 8192, h_bf);
  gemm_big<0><<<dim3(12, 64), 256, 0, stream>>>(h_bf, Wqkv_bf, big, nullptr, 8192, 3072, 1024);
  flash_attn<<<dim3(128, 8), 256, 0, stream>>>(big, h_bf);
  gemm_nt<1><<<dim3(8, 64), 256, 0, stream>>>(h_bf, Wo_bf, x1, x, 8192, 1024, 1024);
  tc_rmsnorm_k<<<8192, 256, 0, stream>>>(x1, gb + 16384, gb + 24576, h_bf);
  gemm_big<0><<<dim3(16, 64), 256, 0, stream>>>(h_bf, gate_bf, big, nullptr, 8192, 4096, 1024);
  gemm_big<2><<<dim3(16, 64), 256, 0, stream>>>(h_bf, hid_bf, big, big, 8192, 4096, 1024);
  gemm_nt<1><<<dim3(8, 64), 256, 0, stream>>>(big, outw_bf, out, x1, 8192, 1024, 4096);
}